// Round 5
// baseline (2708.062 us; speedup 1.0000x reference)
//
#include <hip/hip_runtime.h>
#include <cstdint>
#include <cstddef>

#define U4    512   // 4*U
#define UNITS 128
#define BATCH 256
#define TSEQ  512
#define FEAT  64

// ---------------- fast activations (fp32, ~1e-7 rel err) ----------------
__device__ __forceinline__ float sigm(float x) {
    float e = __expf(-x);
    return __fdividef(1.0f, 1.0f + e);
}
__device__ __forceinline__ float tanh_fast(float x) {
    float e = __expf(2.0f * x);
    return 1.0f - __fdividef(2.0f, e + 1.0f);
}
__device__ __forceinline__ float rl(float v, int lane) {
    return __int_as_float(__builtin_amdgcn_readlane(__float_as_int(v), lane));
}

// ---------------- projection GEMM (unchanged from R1) ----------------
__global__ __launch_bounds__(256, 4)
void proj_gemm(const float* __restrict__ in, const float* __restrict__ W,
               const float* __restrict__ bias, float* __restrict__ out,
               int K, int sB, int sT, int t0, int tcShift)
{
    const int tid = threadIdx.x;
    const int tx = tid & 31;
    const int ty = tid >> 5;
    const int m0 = blockIdx.x * 64;
    const int n0 = blockIdx.y * 128;
    const int TcMask = (1 << tcShift) - 1;

    __shared__ float As[32][68];
    __shared__ float Bs[32][128];

    float4 acc[8];
    #pragma unroll
    for (int i = 0; i < 8; ++i) acc[i] = make_float4(0.f, 0.f, 0.f, 0.f);

    for (int k0 = 0; k0 < K; k0 += 32) {
        #pragma unroll
        for (int i = 0; i < 8; ++i) {
            int l = i * 256 + tid;
            int row = l >> 5, kk = l & 31;
            int rg = m0 + row;
            int b = rg >> tcShift, tc = rg & TcMask;
            As[kk][row] = in[(size_t)b * sB + (size_t)(t0 + tc) * sT + k0 + kk];
        }
        #pragma unroll
        for (int i = 0; i < 4; ++i) {
            int l = i * 256 + tid;
            int kk = l >> 5, jq = l & 31;
            float4 w4 = *(const float4*)(W + (size_t)(k0 + kk) * U4 + n0 + jq * 4);
            *(float4*)(&Bs[kk][jq * 4]) = w4;
        }
        __syncthreads();
        #pragma unroll
        for (int kk = 0; kk < 32; ++kk) {
            float4 b4 = *(const float4*)(&Bs[kk][tx * 4]);
            float4 a0 = *(const float4*)(&As[kk][ty * 8]);
            float4 a1 = *(const float4*)(&As[kk][ty * 8 + 4]);
            float a[8] = {a0.x, a0.y, a0.z, a0.w, a1.x, a1.y, a1.z, a1.w};
            #pragma unroll
            for (int i = 0; i < 8; ++i) {
                acc[i].x = __builtin_fmaf(a[i], b4.x, acc[i].x);
                acc[i].y = __builtin_fmaf(a[i], b4.y, acc[i].y);
                acc[i].z = __builtin_fmaf(a[i], b4.z, acc[i].z);
                acc[i].w = __builtin_fmaf(a[i], b4.w, acc[i].w);
            }
        }
        __syncthreads();
    }

    float4 bb = *(const float4*)(bias + n0 + tx * 4);
    #pragma unroll
    for (int i = 0; i < 8; ++i) {
        int rg = m0 + ty * 8 + i;
        float4 v = acc[i];
        v.x += bb.x; v.y += bb.y; v.z += bb.z; v.w += bb.w;
        *(float4*)(out + (size_t)rg * U4 + n0 + tx * 4) = v;
    }
}

// ---------------- LSTM recurrence ----------------
// 512 threads (8 waves), 1 block/seq, thread j owns full gate-column j
// (128 R values; AGPR residency accepted — the acc_read tax is ~1/3 the cost
// of the barrier stalls it replaces).
// ONE barrier per step:
//   phase A: z_j = xw + sum_k h_k R_kj (readlane broadcast from the wave's
//            OWN registered h copy), activate, write a_j to double-buffered LDS.
//   barrier.
//   phase B: EVERY wave redundantly reads the 8 gate values for its lanes'
//            2 units (conflict-free ds_read) and updates its own registered
//            h (vh0,vh1) and c (c0,c1). No lds_h, no combine wave, no 2nd/3rd
//            barrier (R4 had 3 barriers + a 2-wave serial phase = ~1150
//            stall cyc/step of 2944).
// Double buffer makes 1 barrier sufficient: a wave racing into step t+1
// writes a_buf[buf^1], which no straggler of step t reads.
__global__ __launch_bounds__(512, 2)
void lstm_rec(const float* __restrict__ xw, const float* __restrict__ R,
              float* __restrict__ h_state, float* __restrict__ c_state,
              float* __restrict__ h_out, int Tc, int init)
{
    const int tid  = threadIdx.x;
    const int b    = blockIdx.x;
    const int lane = tid & 63;
    const int wav  = tid >> 6;

    __shared__ float a_buf[2][U4];

    // R column tid into registers: Rr[k] = R[k][tid] (coalesced across lanes)
    float Rr[UNITS];
    #pragma unroll
    for (int k = 0; k < UNITS; ++k) Rr[k] = R[(size_t)k * U4 + tid];

    // per-wave redundant state: lane L holds h[L] (vh0), h[64+L] (vh1), c likewise
    float vh0 = 0.f, vh1 = 0.f, c0 = 0.f, c1 = 0.f;
    if (!init) {
        vh0 = h_state[b * UNITS + lane];
        vh1 = h_state[b * UNITS + 64 + lane];
        c0  = c_state[b * UNITS + lane];
        c1  = c_state[b * UNITS + 64 + lane];
    }

    const float* xwB = xw + (size_t)b * Tc * U4;
    float xwc = xwB[tid];
    int buf = 0;

    #pragma unroll 1
    for (int t = 0; t < Tc; ++t) {
        // ---- phase A: dot + activation ----
        float z0 = xwc, z1 = 0.f, z2 = 0.f, z3 = 0.f;
        #pragma unroll
        for (int k = 0; k < 64; k += 4) {
            z0 = __builtin_fmaf(rl(vh0, k + 0), Rr[k + 0], z0);
            z1 = __builtin_fmaf(rl(vh0, k + 1), Rr[k + 1], z1);
            z2 = __builtin_fmaf(rl(vh0, k + 2), Rr[k + 2], z2);
            z3 = __builtin_fmaf(rl(vh0, k + 3), Rr[k + 3], z3);
        }
        #pragma unroll
        for (int k = 0; k < 64; k += 4) {
            z0 = __builtin_fmaf(rl(vh1, k + 0), Rr[64 + k + 0], z0);
            z1 = __builtin_fmaf(rl(vh1, k + 1), Rr[64 + k + 1], z1);
            z2 = __builtin_fmaf(rl(vh1, k + 2), Rr[64 + k + 2], z2);
            z3 = __builtin_fmaf(rl(vh1, k + 3), Rr[64 + k + 3], z3);
        }
        float zj = (z0 + z1) + (z2 + z3);

        // wave-uniform gate classes: waves 0-3 sigm(i,f), 4-5 tanh(g), 6-7 sigm(o)
        float a;
        if (tid < 256)      a = sigm(zj);
        else if (tid < 384) a = tanh_fast(zj);
        else                a = sigm(zj);
        a_buf[buf][tid] = a;

        // prefetch next xw before the barrier
        int tn = (t + 1 < Tc) ? (t + 1) : t;
        float xwn = xwB[(size_t)tn * U4 + tid];

        __syncthreads();

        // ---- phase B: redundant per-wave h/c update ----
        float iv0 = a_buf[buf][lane];
        float fv0 = a_buf[buf][lane + 128];
        float gv0 = a_buf[buf][lane + 256];
        float ov0 = a_buf[buf][lane + 384];
        float iv1 = a_buf[buf][lane + 64];
        float fv1 = a_buf[buf][lane + 192];
        float gv1 = a_buf[buf][lane + 320];
        float ov1 = a_buf[buf][lane + 448];

        c0 = __builtin_fmaf(fv0, c0, iv0 * gv0);
        c1 = __builtin_fmaf(fv1, c1, iv1 * gv1);
        vh0 = ov0 * tanh_fast(c0);
        vh1 = ov1 * tanh_fast(c1);

        if (h_out && wav == 0) {
            h_out[((size_t)b * Tc + t) * UNITS + lane]      = vh0;
            h_out[((size_t)b * Tc + t) * UNITS + 64 + lane] = vh1;
        }

        xwc = xwn;
        buf ^= 1;
    }

    if (wav == 0) {
        h_state[b * UNITS + lane]      = vh0;
        h_state[b * UNITS + 64 + lane] = vh1;
        c_state[b * UNITS + lane]      = c0;
        c_state[b * UNITS + 64 + lane] = c1;
    }
}

// ---------------- dense head ----------------
__global__ __launch_bounds__(256)
void dense_head(const float* __restrict__ h2, const float* __restrict__ Wd,
                const float* __restrict__ bd, float* __restrict__ out)
{
    int b = threadIdx.x;
    float acc[6];
    #pragma unroll
    for (int o = 0; o < 6; ++o) acc[o] = bd[o];
    #pragma unroll 4
    for (int k = 0; k < UNITS; ++k) {
        float hv = h2[b * UNITS + k];
        #pragma unroll
        for (int o = 0; o < 6; ++o)
            acc[o] = __builtin_fmaf(hv, Wd[k * 6 + o], acc[o]);
    }
    #pragma unroll
    for (int o = 0; o < 6; ++o) out[b * 6 + o] = acc[o];
}

extern "C" void kernel_launch(void* const* d_in, const int* in_sizes, int n_in,
                              void* d_out, int out_size, void* d_ws, size_t ws_size,
                              hipStream_t stream)
{
    (void)in_sizes; (void)n_in; (void)out_size;
    const float* x  = (const float*)d_in[0];
    const float* Ws[3] = {(const float*)d_in[1], (const float*)d_in[4], (const float*)d_in[7]};
    const float* Rs[3] = {(const float*)d_in[2], (const float*)d_in[5], (const float*)d_in[8]};
    const float* bs[3] = {(const float*)d_in[3], (const float*)d_in[6], (const float*)d_in[9]};
    const float* Wd = (const float*)d_in[10];
    const float* bd = (const float*)d_in[11];
    float* out = (float*)d_out;

    int tcShift = 7;
    while (tcShift > 2) {
        size_t need = ((size_t)1 << tcShift) * 655360u + 786432u;
        if (need <= ws_size) break;
        --tcShift;
    }
    const int Tc = 1 << tcShift;

    float* xw = (float*)d_ws;                                // [B][Tc][512]
    float* hc = xw + (size_t)BATCH * Tc * U4;                // [B][Tc][128]
    float* hs = hc + (size_t)BATCH * Tc * UNITS;             // 3 x [B][128]
    float* cs = hs + 3 * BATCH * UNITS;                      // 3 x [B][128]

    const int nChunks = TSEQ / Tc;
    for (int ch = 0; ch < nChunks; ++ch) {
        const int t0 = ch * Tc;
        for (int layer = 0; layer < 3; ++layer) {
            const float* in = (layer == 0) ? x : hc;
            const int K  = (layer == 0) ? FEAT : UNITS;
            const int sB = (layer == 0) ? TSEQ * FEAT : Tc * UNITS;
            const int sT = K;
            const int pt0 = (layer == 0) ? t0 : 0;

            dim3 grid(BATCH * Tc / 64, 4);
            proj_gemm<<<grid, 256, 0, stream>>>(in, Ws[layer], bs[layer], xw,
                                                K, sB, sT, pt0, tcShift);

            float* hOut = (layer < 2) ? hc : nullptr;
            lstm_rec<<<BATCH, 512, 0, stream>>>(xw, Rs[layer],
                                                hs + layer * BATCH * UNITS,
                                                cs + layer * BATCH * UNITS,
                                                hOut, Tc, (ch == 0) ? 1 : 0);
        }
    }
    dense_head<<<1, 256, 0, stream>>>(hs + 2 * BATCH * UNITS, Wd, bd, out);
}

// Round 6
// 2150.918 us; speedup vs baseline: 1.2590x; 1.2590x over previous
//
#include <hip/hip_runtime.h>
#include <cstdint>
#include <cstddef>

#define U4    512   // 4*U
#define UNITS 128
#define BATCH 256
#define TSEQ  512
#define FEAT  64

// ---------------- fast activations (fp32, ~1e-7 rel err) ----------------
__device__ __forceinline__ float sigm(float x) {
    float e = __expf(-x);
    return __fdividef(1.0f, 1.0f + e);
}
__device__ __forceinline__ float tanh_fast(float x) {
    float e = __expf(2.0f * x);
    return 1.0f - __fdividef(2.0f, e + 1.0f);
}

// ---------------- projection GEMM (unchanged from R1) ----------------
__global__ __launch_bounds__(256, 4)
void proj_gemm(const float* __restrict__ in, const float* __restrict__ W,
               const float* __restrict__ bias, float* __restrict__ out,
               int K, int sB, int sT, int t0, int tcShift)
{
    const int tid = threadIdx.x;
    const int tx = tid & 31;
    const int ty = tid >> 5;
    const int m0 = blockIdx.x * 64;
    const int n0 = blockIdx.y * 128;
    const int TcMask = (1 << tcShift) - 1;

    __shared__ float As[32][68];
    __shared__ float Bs[32][128];

    float4 acc[8];
    #pragma unroll
    for (int i = 0; i < 8; ++i) acc[i] = make_float4(0.f, 0.f, 0.f, 0.f);

    for (int k0 = 0; k0 < K; k0 += 32) {
        #pragma unroll
        for (int i = 0; i < 8; ++i) {
            int l = i * 256 + tid;
            int row = l >> 5, kk = l & 31;
            int rg = m0 + row;
            int b = rg >> tcShift, tc = rg & TcMask;
            As[kk][row] = in[(size_t)b * sB + (size_t)(t0 + tc) * sT + k0 + kk];
        }
        #pragma unroll
        for (int i = 0; i < 4; ++i) {
            int l = i * 256 + tid;
            int kk = l >> 5, jq = l & 31;
            float4 w4 = *(const float4*)(W + (size_t)(k0 + kk) * U4 + n0 + jq * 4);
            *(float4*)(&Bs[kk][jq * 4]) = w4;
        }
        __syncthreads();
        #pragma unroll
        for (int kk = 0; kk < 32; ++kk) {
            float4 b4 = *(const float4*)(&Bs[kk][tx * 4]);
            float4 a0 = *(const float4*)(&As[kk][ty * 8]);
            float4 a1 = *(const float4*)(&As[kk][ty * 8 + 4]);
            float a[8] = {a0.x, a0.y, a0.z, a0.w, a1.x, a1.y, a1.z, a1.w};
            #pragma unroll
            for (int i = 0; i < 8; ++i) {
                acc[i].x = __builtin_fmaf(a[i], b4.x, acc[i].x);
                acc[i].y = __builtin_fmaf(a[i], b4.y, acc[i].y);
                acc[i].z = __builtin_fmaf(a[i], b4.z, acc[i].z);
                acc[i].w = __builtin_fmaf(a[i], b4.w, acc[i].w);
            }
        }
        __syncthreads();
    }

    float4 bb = *(const float4*)(bias + n0 + tx * 4);
    #pragma unroll
    for (int i = 0; i < 8; ++i) {
        int rg = m0 + ty * 8 + i;
        float4 v = acc[i];
        v.x += bb.x; v.y += bb.y; v.z += bb.z; v.w += bb.w;
        *(float4*)(out + (size_t)rg * U4 + n0 + tx * 4) = v;
    }
}

// ---------------- LSTM recurrence ----------------
// 512 threads (8 waves), 1 block/seq, thread j owns full gate-column j.
// KEY change vs R5: h broadcast via uniform-address ds_read_b128 from LDS
// (4 h/instr, LDS-pipe, broadcast fast path) instead of v_readlane. This
// puts h in VGPRs, so fma = v_fmac(vH, vR) — no SGPR slot consumed, so the
// AGPR-resident R costs at most 1 acc_read/MAC (R1-R5 paid readlane +
// acc_read + fma = 3 VALU/MAC because SGPR-h forced R out of vsrc1).
// Single barrier per step, double-buffered h_lds AND a_buf; every wave
// redundantly computes/writes the FULL h array (same-value races benign),
// so each wave always reads its own h writes -> no write->read barrier.
__global__ __launch_bounds__(512, 2)
void lstm_rec(const float* __restrict__ xw, const float* __restrict__ R,
              float* __restrict__ h_state, float* __restrict__ c_state,
              float* __restrict__ h_out, int Tc, int init)
{
    const int j    = threadIdx.x;
    const int b    = blockIdx.x;
    const int lane = j & 63;
    const int wav  = j >> 6;

    __shared__ __align__(16) float h_lds[2][UNITS];
    __shared__ float a_buf[2][U4];

    // R column j into registers: Rr[k] = R[k][j] (coalesced across lanes)
    float Rr[UNITS];
    #pragma unroll
    for (int k = 0; k < UNITS; ++k) Rr[k] = R[(size_t)k * U4 + j];

    // per-wave registered c for units (lane, lane+64); initial h into h_lds[0]
    float c0 = 0.f, c1 = 0.f, hv0 = 0.f, hv1 = 0.f;
    if (!init) {
        hv0 = h_state[b * UNITS + lane];
        hv1 = h_state[b * UNITS + 64 + lane];
        c0  = c_state[b * UNITS + lane];
        c1  = c_state[b * UNITS + 64 + lane];
    }
    // every wave writes the full h array (redundant, identical values)
    h_lds[0][lane]      = hv0;
    h_lds[0][64 + lane] = hv1;

    const float* xwB = xw + (size_t)b * Tc * U4;
    float xwc = xwB[j];
    int p = 0;

    #pragma unroll 1
    for (int t = 0; t < Tc; ++t) {
        // ---- phase A: z_j = xw_j + sum_k h_k R_kj ----
        const float* hb = &h_lds[p][0];
        float z0 = xwc, z1 = 0.f, z2 = 0.f, z3 = 0.f;
        #pragma unroll
        for (int k = 0; k < UNITS; k += 8) {
            float4 h4a = *(const float4*)(hb + k);      // uniform ds_read_b128
            float4 h4b = *(const float4*)(hb + k + 4);
            z0 = __builtin_fmaf(h4a.x, Rr[k + 0], z0);
            z1 = __builtin_fmaf(h4a.y, Rr[k + 1], z1);
            z2 = __builtin_fmaf(h4a.z, Rr[k + 2], z2);
            z3 = __builtin_fmaf(h4a.w, Rr[k + 3], z3);
            z0 = __builtin_fmaf(h4b.x, Rr[k + 4], z0);
            z1 = __builtin_fmaf(h4b.y, Rr[k + 5], z1);
            z2 = __builtin_fmaf(h4b.z, Rr[k + 6], z2);
            z3 = __builtin_fmaf(h4b.w, Rr[k + 7], z3);
        }
        float zj = (z0 + z1) + (z2 + z3);

        // wave-uniform gate classes: waves 0-3 sigm(i,f), 4-5 tanh(g), 6-7 sigm(o)
        float a;
        if (j < 256)      a = sigm(zj);
        else if (j < 384) a = tanh_fast(zj);
        else              a = sigm(zj);
        a_buf[p][j] = a;

        // prefetch next xw before the barrier
        int tn = (t + 1 < Tc) ? (t + 1) : t;
        float xwn = xwB[(size_t)tn * U4 + j];

        __syncthreads();   // the ONE barrier: a_buf[p] complete

        // ---- phase B: redundant h/c update in every wave ----
        float iv0 = a_buf[p][lane];
        float fv0 = a_buf[p][lane + 128];
        float gv0 = a_buf[p][lane + 256];
        float ov0 = a_buf[p][lane + 384];
        float iv1 = a_buf[p][lane + 64];
        float fv1 = a_buf[p][lane + 192];
        float gv1 = a_buf[p][lane + 320];
        float ov1 = a_buf[p][lane + 448];

        c0 = __builtin_fmaf(fv0, c0, iv0 * gv0);
        c1 = __builtin_fmaf(fv1, c1, iv1 * gv1);
        hv0 = ov0 * tanh_fast(c0);
        hv1 = ov1 * tanh_fast(c1);
        h_lds[p ^ 1][lane]      = hv0;   // every wave writes full h
        h_lds[p ^ 1][64 + lane] = hv1;

        if (h_out && wav == 0) {
            h_out[((size_t)b * Tc + t) * UNITS + lane]      = hv0;
            h_out[((size_t)b * Tc + t) * UNITS + 64 + lane] = hv1;
        }

        xwc = xwn;
        p ^= 1;
    }

    if (wav == 0) {
        h_state[b * UNITS + lane]      = hv0;
        h_state[b * UNITS + 64 + lane] = hv1;
        c_state[b * UNITS + lane]      = c0;
        c_state[b * UNITS + 64 + lane] = c1;
    }
}

// ---------------- dense head ----------------
__global__ __launch_bounds__(256)
void dense_head(const float* __restrict__ h2, const float* __restrict__ Wd,
                const float* __restrict__ bd, float* __restrict__ out)
{
    int b = threadIdx.x;
    float acc[6];
    #pragma unroll
    for (int o = 0; o < 6; ++o) acc[o] = bd[o];
    #pragma unroll 4
    for (int k = 0; k < UNITS; ++k) {
        float hv = h2[b * UNITS + k];
        #pragma unroll
        for (int o = 0; o < 6; ++o)
            acc[o] = __builtin_fmaf(hv, Wd[k * 6 + o], acc[o]);
    }
    #pragma unroll
    for (int o = 0; o < 6; ++o) out[b * 6 + o] = acc[o];
}

extern "C" void kernel_launch(void* const* d_in, const int* in_sizes, int n_in,
                              void* d_out, int out_size, void* d_ws, size_t ws_size,
                              hipStream_t stream)
{
    (void)in_sizes; (void)n_in; (void)out_size;
    const float* x  = (const float*)d_in[0];
    const float* Ws[3] = {(const float*)d_in[1], (const float*)d_in[4], (const float*)d_in[7]};
    const float* Rs[3] = {(const float*)d_in[2], (const float*)d_in[5], (const float*)d_in[8]};
    const float* bs[3] = {(const float*)d_in[3], (const float*)d_in[6], (const float*)d_in[9]};
    const float* Wd = (const float*)d_in[10];
    const float* bd = (const float*)d_in[11];
    float* out = (float*)d_out;

    int tcShift = 7;
    while (tcShift > 2) {
        size_t need = ((size_t)1 << tcShift) * 655360u + 786432u;
        if (need <= ws_size) break;
        --tcShift;
    }
    const int Tc = 1 << tcShift;

    float* xw = (float*)d_ws;                                // [B][Tc][512]
    float* hc = xw + (size_t)BATCH * Tc * U4;                // [B][Tc][128]
    float* hs = hc + (size_t)BATCH * Tc * UNITS;             // 3 x [B][128]
    float* cs = hs + 3 * BATCH * UNITS;                      // 3 x [B][128]

    const int nChunks = TSEQ / Tc;
    for (int ch = 0; ch < nChunks; ++ch) {
        const int t0 = ch * Tc;
        for (int layer = 0; layer < 3; ++layer) {
            const float* in = (layer == 0) ? x : hc;
            const int K  = (layer == 0) ? FEAT : UNITS;
            const int sB = (layer == 0) ? TSEQ * FEAT : Tc * UNITS;
            const int sT = K;
            const int pt0 = (layer == 0) ? t0 : 0;

            dim3 grid(BATCH * Tc / 64, 4);
            proj_gemm<<<grid, 256, 0, stream>>>(in, Ws[layer], bs[layer], xw,
                                                K, sB, sT, pt0, tcShift);

            float* hOut = (layer < 2) ? hc : nullptr;
            lstm_rec<<<BATCH, 512, 0, stream>>>(xw, Rs[layer],
                                                hs + layer * BATCH * UNITS,
                                                cs + layer * BATCH * UNITS,
                                                hOut, Tc, (ch == 0) ? 1 : 0);
        }
    }
    dense_head<<<1, 256, 0, stream>>>(hs + 2 * BATCH * UNITS, Wd, bd, out);
}